// Round 4
// baseline (232.932 us; speedup 1.0000x reference)
//
#include <hip/hip_runtime.h>
#include <hip/hip_bf16.h>

// GAT: N=4096 nodes, IN_F=256, H=4 heads, D=64.
// K0 gat_pack : adj (64 MB int) -> adjb bitmask (2 MB), coalesced streaming.
// K1 gat_prep : h = x@W (fp32), siT = <h,a1>*log2e, vT = exp2(<h,a2>*log2e),
//               v2T = exp2(0.2*...), hT bf16 [H][D][N], per-block sj-max partials.
// K2 gat_attn : masked softmax + PV via mfma_16x16x32_bf16.
//               m_i = leaky(si + max_j sj) upper bound -> pure-sum softmax.
//               8 waves split j (512 each); two-phase LDS combine; direct out.
//               sched_barrier pins the load prefetch ahead of compute.

typedef __bf16 bf16x8 __attribute__((ext_vector_type(8)));
typedef float floatx4 __attribute__((ext_vector_type(4)));

#define LOG2E 1.4426950408889634f
#define NN 4096

// ---------------- Kernel 0: adj -> bitmask ----------------
__global__ __launch_bounds__(256) void gat_pack(const int* __restrict__ adj,
                                                unsigned char* __restrict__ adjb) {
  int T = blockIdx.x * 256 + threadIdx.x;
  const int stride = 2048 * 256;
#pragma unroll
  for (int it = 0; it < 4; ++it, T += stride) {
    const int* p = adj + (size_t)T * 8;
    int4 a = *(const int4*)p;
    int4 b = *(const int4*)(p + 4);
    unsigned int m = 0;
    m |= (a.x != 0) ? 1u : 0u;
    m |= (a.y != 0) ? 2u : 0u;
    m |= (a.z != 0) ? 4u : 0u;
    m |= (a.w != 0) ? 8u : 0u;
    m |= (b.x != 0) ? 16u : 0u;
    m |= (b.y != 0) ? 32u : 0u;
    m |= (b.z != 0) ? 64u : 0u;
    m |= (b.w != 0) ? 128u : 0u;
    adjb[T] = (unsigned char)m;
  }
}

// ---------------- Kernel 1: h = x@W + per-row scalars + hT(bf16) ----------------
__global__ __launch_bounds__(256) void gat_prep(
    const float* __restrict__ x, const float* __restrict__ W,
    const float* __restrict__ a1, const float* __restrict__ a2,
    __bf16* __restrict__ hT, float* __restrict__ siT, float* __restrict__ vT,
    float* __restrict__ v2T, float* __restrict__ sjm) {
  __shared__ float hl[32 * 68];
  __shared__ float sjb[32];
  const int t = threadIdx.x;
  const int it = blockIdx.x, hh = blockIdx.y;
  const int i0 = it * 32, c0 = hh * 64;
  const int tr = t >> 4, tc = t & 15;

  float acc[2][4] = {{0.f,0.f,0.f,0.f},{0.f,0.f,0.f,0.f}};
  const float* xr = x + (size_t)(i0 + tr * 2) * 256;
  const float* wp = W + c0 + tc * 4;
  for (int k = 0; k < 256; k += 4) {
    float4 xv0 = *(const float4*)(xr + k);
    float4 xv1 = *(const float4*)(xr + 256 + k);
    float xs[2][4] = {{xv0.x, xv0.y, xv0.z, xv0.w},
                      {xv1.x, xv1.y, xv1.z, xv1.w}};
#pragma unroll
    for (int kk = 0; kk < 4; ++kk) {
      float4 wv = *(const float4*)(wp + (size_t)(k + kk) * 256);
#pragma unroll
      for (int i = 0; i < 2; ++i) {
        acc[i][0] = fmaf(xs[i][kk], wv.x, acc[i][0]);
        acc[i][1] = fmaf(xs[i][kk], wv.y, acc[i][1]);
        acc[i][2] = fmaf(xs[i][kk], wv.z, acc[i][2]);
        acc[i][3] = fmaf(xs[i][kk], wv.w, acc[i][3]);
      }
    }
  }

  float4 a1v = *(const float4*)(a1 + tc * 4);
  float4 a2v = *(const float4*)(a2 + tc * 4);
#pragma unroll
  for (int i = 0; i < 2; ++i) {
    float s1 = acc[i][0]*a1v.x + acc[i][1]*a1v.y + acc[i][2]*a1v.z + acc[i][3]*a1v.w;
    float s2 = acc[i][0]*a2v.x + acc[i][1]*a2v.y + acc[i][2]*a2v.z + acc[i][3]*a2v.w;
#pragma unroll
    for (int off = 1; off < 16; off <<= 1) {
      s1 += __shfl_xor(s1, off);
      s2 += __shfl_xor(s2, off);
    }
    if (tc == 0) {
      int r = tr * 2 + i;
      siT[hh * NN + i0 + r] = s1 * LOG2E;
      float sjs = s2 * LOG2E;
      vT[hh * NN + i0 + r] = __builtin_amdgcn_exp2f(sjs);
      v2T[hh * NN + i0 + r] = __builtin_amdgcn_exp2f(0.2f * sjs);
      sjb[r] = sjs;
    }
    *(float4*)&hl[(tr * 2 + i) * 68 + tc * 4] =
        make_float4(acc[i][0], acc[i][1], acc[i][2], acc[i][3]);
  }
  __syncthreads();

  if (t < 32) {
    float v = sjb[t];
#pragma unroll
    for (int off = 1; off < 32; off <<= 1) v = fmaxf(v, __shfl_xor(v, off));
    if (t == 0) sjm[it * 4 + hh] = v;
  }

  const int d = t & 63, g = t >> 6;
  bf16x8 h0;
#pragma unroll
  for (int ii = 0; ii < 8; ++ii) h0[ii] = (__bf16)hl[(g * 8 + ii) * 68 + d];
  *(bf16x8*)(hT + (size_t)(hh * 64 + d) * NN + i0 + g * 8) = h0;
}

// ---------------- Kernel 2: masked softmax + PV (MFMA), direct out ----------------
// grid (128 i-tiles of 32, 4 heads), 512 threads = 8 waves; wave w owns j-slice
// [w*512, w*512+512). Two-phase LDS combine, then normalize + write out.
__global__ __launch_bounds__(512, 4) void gat_attn(
    const unsigned int* __restrict__ adjw, const __bf16* __restrict__ hT,
    const float* __restrict__ siT, const float* __restrict__ vT,
    const float* __restrict__ v2T, const float* __restrict__ sjm,
    float* __restrict__ out) {
  __shared__ float accs[4][32][68];
  __shared__ float lsum[4][32];
  const int t = threadIdx.x;
  const int w = t >> 6, lane = t & 63, quad = lane >> 4, l16 = lane & 15;
  const int i0 = blockIdx.x * 32;
  const int hh = blockIdx.y;

  // global sj-max for this head (128 block-partials)
  float vv = fmaxf(sjm[lane * 4 + hh], sjm[(lane + 64) * 4 + hh]);
#pragma unroll
  for (int off = 1; off < 64; off <<= 1) vv = fmaxf(vv, __shfl_xor(vv, off));

  float u[2], u2[2];
#pragma unroll
  for (int mt = 0; mt < 2; ++mt) {
    float sis = siT[hh * NN + i0 + mt * 16 + l16];
    float tt = sis + vv;
    float m = fmaxf(tt, 0.2f * tt);   // leaky monotone -> valid row-max upper bound
    u[mt] = __builtin_amdgcn_exp2f(sis - m);
    u2[mt] = __builtin_amdgcn_exp2f(0.2f * sis - m);
  }

  bf16x8 ones;
#pragma unroll
  for (int ii = 0; ii < 8; ++ii) ones[ii] = (__bf16)1.0f;

  floatx4 zv = {0.f, 0.f, 0.f, 0.f};
  floatx4 acc[2][4], lacc[2];
#pragma unroll
  for (int mt = 0; mt < 2; ++mt) {
    lacc[mt] = zv;
#pragma unroll
    for (int nt = 0; nt < 4; ++nt) acc[mt][nt] = zv;
  }

  const __bf16* hTw = hT + (size_t)hh * 64 * NN;
  const float* vw = vT + hh * NN;
  const float* v2w = v2T + hh * NN;
  const unsigned int* ar0 = adjw + (size_t)(i0 + l16) * 128;
  const unsigned int* ar1 = adjw + (size_t)(i0 + 16 + l16) * 128;

  const int jbeg = w * 512, jend = jbeg + 512;

#define STAGE(J, BF, VA, VB, V2A, V2B)                                          \
  {                                                                             \
    _Pragma("unroll")                                                           \
    for (int nt = 0; nt < 4; ++nt)                                              \
      BF[nt] = *(const bf16x8*)(hTw + (size_t)(nt * 16 + l16) * NN + (J) + quad * 8); \
    VA = *(const float4*)(vw + (J) + quad * 8);                                 \
    VB = *(const float4*)(vw + (J) + quad * 8 + 4);                             \
    V2A = *(const float4*)(v2w + (J) + quad * 8);                               \
    V2B = *(const float4*)(v2w + (J) + quad * 8 + 4);                           \
  }

#define COMPUTE(WA, WB, BF, VA, VB, V2A, V2B)                                   \
  {                                                                             \
    float vj[8] = {VA.x, VA.y, VA.z, VA.w, VB.x, VB.y, VB.z, VB.w};             \
    float v2j[8] = {V2A.x, V2A.y, V2A.z, V2A.w, V2B.x, V2B.y, V2B.z, V2B.w};    \
    _Pragma("unroll")                                                           \
    for (int mt = 0; mt < 2; ++mt) {                                            \
      unsigned int m8 = ((mt ? (WB) : (WA)) >> (quad * 8));                     \
      bf16x8 af;                                                                \
      _Pragma("unroll")                                                         \
      for (int jj = 0; jj < 8; ++jj) {                                          \
        float p = fmaxf(u[mt] * vj[jj], u2[mt] * v2j[jj]);                      \
        af[jj] = ((m8 >> jj) & 1u) ? (__bf16)p : (__bf16)0.f;                   \
      }                                                                         \
      _Pragma("unroll")                                                         \
      for (int nt = 0; nt < 4; ++nt)                                            \
        acc[mt][nt] = __builtin_amdgcn_mfma_f32_16x16x32_bf16(af, BF[nt],       \
                                                              acc[mt][nt], 0, 0, 0); \
      lacc[mt] = __builtin_amdgcn_mfma_f32_16x16x32_bf16(af, ones,              \
                                                         lacc[mt], 0, 0, 0);    \
    }                                                                           \
  }

  bf16x8 bfc[4], bfn[4];
  float4 vac, vbc, v2ac, v2bc, van, vbn, v2an, v2bn;
  uint2 m0c, m1c, m0n, m1n;

  m0c = *(const uint2*)(ar0 + (jbeg >> 5));   // 64 j of row l16
  m1c = *(const uint2*)(ar1 + (jbeg >> 5));   // 64 j of row 16+l16
  STAGE(jbeg, bfc, vac, vbc, v2ac, v2bc);

  for (int j0 = jbeg; j0 < jend; j0 += 64) {
    // prefetch step B of this iter + adj of next iter
    STAGE(j0 + 32, bfn, van, vbn, v2an, v2bn);
    if (j0 + 64 < jend) {
      m0n = *(const uint2*)(ar0 + ((j0 + 64) >> 5));
      m1n = *(const uint2*)(ar1 + ((j0 + 64) >> 5));
    }
    __builtin_amdgcn_sched_barrier(0);  // keep prefetch ahead of compute
    COMPUTE(m0c.x, m1c.x, bfc, vac, vbc, v2ac, v2bc);
    if (j0 + 64 < jend) STAGE(j0 + 64, bfc, vac, vbc, v2ac, v2bc);
    __builtin_amdgcn_sched_barrier(0);
    COMPUTE(m0c.y, m1c.y, bfn, van, vbn, v2an, v2bn);
    m0c = m0n; m1c = m1n;
  }

  // two-phase combine across 8 waves (waves 4-7 fold into buffers 0-3)
  // C layout: row = mt*16 + quad*4 + reg, col = nt*16 + l16
  if (w < 4) {
#pragma unroll
    for (int mt = 0; mt < 2; ++mt)
#pragma unroll
      for (int reg = 0; reg < 4; ++reg) {
        int row = mt * 16 + quad * 4 + reg;
#pragma unroll
        for (int nt = 0; nt < 4; ++nt)
          accs[w][row][nt * 16 + l16] = acc[mt][nt][reg];
        if (l16 == 0) lsum[w][row] = lacc[mt][reg];
      }
  }
  __syncthreads();
  if (w >= 4) {
    const int b = w - 4;
#pragma unroll
    for (int mt = 0; mt < 2; ++mt)
#pragma unroll
      for (int reg = 0; reg < 4; ++reg) {
        int row = mt * 16 + quad * 4 + reg;
#pragma unroll
        for (int nt = 0; nt < 4; ++nt)
          accs[b][row][nt * 16 + l16] += acc[mt][nt][reg];
        if (l16 == 0) lsum[b][row] += lacc[mt][reg];
      }
  }
  __syncthreads();

  // 512 threads: r = t>>4 (32 rows), c = (t&15)*4 (64 cols)
  const int r = t >> 4, c = (t & 15) * 4;
  float l = lsum[0][r] + lsum[1][r] + lsum[2][r] + lsum[3][r];
  float inv = 1.0f / l;
  float4 o;
  o.x = (accs[0][r][c+0] + accs[1][r][c+0] + accs[2][r][c+0] + accs[3][r][c+0]) * inv;
  o.y = (accs[0][r][c+1] + accs[1][r][c+1] + accs[2][r][c+1] + accs[3][r][c+1]) * inv;
  o.z = (accs[0][r][c+2] + accs[1][r][c+2] + accs[2][r][c+2] + accs[3][r][c+2]) * inv;
  o.w = (accs[0][r][c+3] + accs[1][r][c+3] + accs[2][r][c+3] + accs[3][r][c+3]) * inv;
  *(float4*)(out + (size_t)(i0 + r) * 256 + hh * 64 + c) = o;
}

extern "C" void kernel_launch(void* const* d_in, const int* in_sizes, int n_in,
                              void* d_out, int out_size, void* d_ws, size_t ws_size,
                              hipStream_t stream) {
  const float* x  = (const float*)d_in[0];
  const int*   adj = (const int*)d_in[1];
  const float* W  = (const float*)d_in[2];
  const float* a1 = (const float*)d_in[3];
  const float* a2 = (const float*)d_in[4];
  float* out = (float*)d_out;
  char* ws = (char*)d_ws;

  // ws layout (bytes):
  //   hT   bf16 [4][64][4096]  @ 0        (2 MiB)
  //   siT  f32  [4][4096]      @ 2097152
  //   vT   f32  [4][4096]      @ 2162688
  //   v2T  f32  [4][4096]      @ 2228224
  //   sjm  f32  [128][4]       @ 2293760  (2 KiB)
  //   adjb u8   [4096][512]    @ 2295808  (2 MiB bitmask)
  __bf16* hT  = (__bf16*)ws;
  float* siT  = (float*)(ws + 2097152);
  float* vT   = (float*)(ws + 2162688);
  float* v2T  = (float*)(ws + 2228224);
  float* sjm  = (float*)(ws + 2293760);
  unsigned char* adjb = (unsigned char*)(ws + 2295808);

  gat_pack<<<2048, 256, 0, stream>>>(adj, adjb);
  gat_prep<<<dim3(128, 4), 256, 0, stream>>>(x, W, a1, a2, hT, siT, vT, v2T, sjm);
  gat_attn<<<dim3(128, 4), 512, 0, stream>>>((const unsigned int*)adjb, hT, siT, vT,
                                             v2T, sjm, out);
}

// Round 5
// 164.993 us; speedup vs baseline: 1.4118x; 1.4118x over previous
//
#include <hip/hip_runtime.h>
#include <hip/hip_bf16.h>

// GAT: N=4096 nodes, IN_F=256, H=4 heads, D=64.
// K0 gat_pack : adj (64 MB int) -> adjb bitmask (2 MB), coalesced streaming.
// K1 gat_prep : h = x@W (fp32), siT = <h,a1>*log2e, vv2T = {exp2(sj), exp2(0.2*sj)},
//               hT bf16 [H][D][N], per-block sj-max partials.
// K2 gat_attn : masked softmax + PV via mfma_16x16x32_bf16.
//               m_i = leaky(si + max_j sj) upper bound -> pure-sum softmax.
//               Per-128-j window: global_load_lds stages hT in MFMA-fragment lane
//               order (contiguous ds_read_b128 back) + vv2; adj bitmask staged once
//               (XOR-swizzled chunks). Double-buffered, 1 barrier/window.
//               p_ij = max(u_i*v_j, u2_i*v2_j): no transcendentals in hot loop.

typedef __bf16 bf16x8 __attribute__((ext_vector_type(8)));
typedef float floatx4 __attribute__((ext_vector_type(4)));

#define LOG2E 1.4426950408889634f
#define NN 4096

__device__ __forceinline__ void gl16(const void* g, void* l) {
  __builtin_amdgcn_global_load_lds(
      (const __attribute__((address_space(1))) unsigned int*)g,
      (__attribute__((address_space(3))) unsigned int*)l, 16, 0, 0);
}

// ---------------- Kernel 0: adj -> bitmask ----------------
__global__ __launch_bounds__(256) void gat_pack(const int* __restrict__ adj,
                                                unsigned char* __restrict__ adjb) {
  int T = blockIdx.x * 256 + threadIdx.x;
  const int stride = 2048 * 256;
#pragma unroll
  for (int it = 0; it < 4; ++it, T += stride) {
    const int* p = adj + (size_t)T * 8;
    int4 a = *(const int4*)p;
    int4 b = *(const int4*)(p + 4);
    unsigned int m = 0;
    m |= (a.x != 0) ? 1u : 0u;
    m |= (a.y != 0) ? 2u : 0u;
    m |= (a.z != 0) ? 4u : 0u;
    m |= (a.w != 0) ? 8u : 0u;
    m |= (b.x != 0) ? 16u : 0u;
    m |= (b.y != 0) ? 32u : 0u;
    m |= (b.z != 0) ? 64u : 0u;
    m |= (b.w != 0) ? 128u : 0u;
    adjb[T] = (unsigned char)m;
  }
}

// ---------------- Kernel 1: h = x@W + per-row scalars + hT(bf16) ----------------
__global__ __launch_bounds__(256) void gat_prep(
    const float* __restrict__ x, const float* __restrict__ W,
    const float* __restrict__ a1, const float* __restrict__ a2,
    __bf16* __restrict__ hT, float* __restrict__ siT, float2* __restrict__ vv2T,
    float* __restrict__ sjm) {
  __shared__ float hl[32 * 68];
  __shared__ float sjb[32];
  const int t = threadIdx.x;
  const int it = blockIdx.x, hh = blockIdx.y;
  const int i0 = it * 32, c0 = hh * 64;
  const int tr = t >> 4, tc = t & 15;

  float acc[2][4] = {{0.f,0.f,0.f,0.f},{0.f,0.f,0.f,0.f}};
  const float* xr = x + (size_t)(i0 + tr * 2) * 256;
  const float* wp = W + c0 + tc * 4;
  for (int k = 0; k < 256; k += 4) {
    float4 xv0 = *(const float4*)(xr + k);
    float4 xv1 = *(const float4*)(xr + 256 + k);
    float xs[2][4] = {{xv0.x, xv0.y, xv0.z, xv0.w},
                      {xv1.x, xv1.y, xv1.z, xv1.w}};
#pragma unroll
    for (int kk = 0; kk < 4; ++kk) {
      float4 wv = *(const float4*)(wp + (size_t)(k + kk) * 256);
#pragma unroll
      for (int i = 0; i < 2; ++i) {
        acc[i][0] = fmaf(xs[i][kk], wv.x, acc[i][0]);
        acc[i][1] = fmaf(xs[i][kk], wv.y, acc[i][1]);
        acc[i][2] = fmaf(xs[i][kk], wv.z, acc[i][2]);
        acc[i][3] = fmaf(xs[i][kk], wv.w, acc[i][3]);
      }
    }
  }

  float4 a1v = *(const float4*)(a1 + tc * 4);
  float4 a2v = *(const float4*)(a2 + tc * 4);
#pragma unroll
  for (int i = 0; i < 2; ++i) {
    float s1 = acc[i][0]*a1v.x + acc[i][1]*a1v.y + acc[i][2]*a1v.z + acc[i][3]*a1v.w;
    float s2 = acc[i][0]*a2v.x + acc[i][1]*a2v.y + acc[i][2]*a2v.z + acc[i][3]*a2v.w;
#pragma unroll
    for (int off = 1; off < 16; off <<= 1) {
      s1 += __shfl_xor(s1, off);
      s2 += __shfl_xor(s2, off);
    }
    if (tc == 0) {
      int r = tr * 2 + i;
      siT[hh * NN + i0 + r] = s1 * LOG2E;
      float sjs = s2 * LOG2E;
      vv2T[hh * NN + i0 + r] =
          make_float2(__builtin_amdgcn_exp2f(sjs), __builtin_amdgcn_exp2f(0.2f * sjs));
      sjb[r] = sjs;
    }
    *(float4*)&hl[(tr * 2 + i) * 68 + tc * 4] =
        make_float4(acc[i][0], acc[i][1], acc[i][2], acc[i][3]);
  }
  __syncthreads();

  if (t < 32) {
    float v = sjb[t];
#pragma unroll
    for (int off = 1; off < 32; off <<= 1) v = fmaxf(v, __shfl_xor(v, off));
    if (t == 0) sjm[it * 4 + hh] = v;
  }

  const int d = t & 63, g = t >> 6;
  bf16x8 h0;
#pragma unroll
  for (int ii = 0; ii < 8; ++ii) h0[ii] = (__bf16)hl[(g * 8 + ii) * 68 + d];
  *(bf16x8*)(hT + (size_t)(hh * 64 + d) * NN + i0 + g * 8) = h0;
}

// ---------------- Kernel 2: masked softmax + PV (MFMA), direct out ----------------
// grid (128 i-tiles of 32, 4 heads), 256 threads = 4 waves; wave w owns j-offset
// w*32 within each 128-j window; 32 windows cover j=0..4095.
__global__ __launch_bounds__(256, 2) void gat_attn(
    const __bf16* __restrict__ hT, const float* __restrict__ siT,
    const float2* __restrict__ vv2T, const float* __restrict__ sjm,
    const unsigned char* __restrict__ adjb, float* __restrict__ out) {
  // LDS: [0,16384) hT frag buf0 | [16384,32768) hT frag buf1
  //      [32768,33792) vv2 buf0 | [33792,34816) vv2 buf1
  //      [34816,51200) adj bitmask rows (XOR-swizzled 16B chunks)
  // epilogue alias: accs f32[4][32][68] @0 (34816 B), lsum f32[4][32] @34816
  __shared__ __align__(16) char lds[51200];
  const int t = threadIdx.x;
  const int w = t >> 6, lane = t & 63, quad = lane >> 4, l16 = lane & 15;
  const int i0 = blockIdx.x * 32, hh = blockIdx.y;

  const __bf16* hTw = hT + (size_t)hh * 64 * NN;
  const float2* vw = vv2T + hh * NN;

  // ---- stage adj rows once: row r chunk c -> slot c^r (16B chunks) ----
#pragma unroll
  for (int k = 0; k < 4; ++k) {
    int s = (w * 4 + k) * 64 + lane;
    int r = s >> 5, slot = s & 31, c = slot ^ r;
    gl16(adjb + (size_t)(i0 + r) * 512 + c * 16, lds + 34816 + s * 16);
  }

  // per-lane hT fragment gather offsets (elements)
  int hoff[4];
#pragma unroll
  for (int nt = 0; nt < 4; ++nt)
    hoff[nt] = (nt * 16 + l16) * NN + w * 32 + quad * 8;

  // ---- stage window 0 into buf0 ----
#pragma unroll
  for (int nt = 0; nt < 4; ++nt)
    gl16(hTw + hoff[nt], lds + ((w * 4 + nt) << 10) + (lane << 4));
  if (w == 0)
    gl16(vw + (quad * 32 + l16 * 2), lds + 32768 + (lane << 4));

  // ---- per-row constants (overlaps staging) ----
  float vv = fmaxf(sjm[lane * 4 + hh], sjm[(lane + 64) * 4 + hh]);
#pragma unroll
  for (int off = 1; off < 64; off <<= 1) vv = fmaxf(vv, __shfl_xor(vv, off));
  float u[2], u2[2];
#pragma unroll
  for (int mt = 0; mt < 2; ++mt) {
    float sis = siT[hh * NN + i0 + mt * 16 + l16];
    float tt = sis + vv;
    float m = fmaxf(tt, 0.2f * tt);   // leaky monotone -> valid row-max upper bound
    u[mt] = __builtin_amdgcn_exp2f(sis - m);
    u2[mt] = __builtin_amdgcn_exp2f(0.2f * sis - m);
  }

  bf16x8 ones;
#pragma unroll
  for (int ii = 0; ii < 8; ++ii) ones[ii] = (__bf16)1.0f;

  floatx4 zv = {0.f, 0.f, 0.f, 0.f};
  floatx4 acc[2][4], lacc[2];
#pragma unroll
  for (int mt = 0; mt < 2; ++mt) {
    lacc[mt] = zv;
#pragma unroll
    for (int nt = 0; nt < 4; ++nt) acc[mt][nt] = zv;
  }

  __syncthreads();   // window 0 + adj staged

  for (int win = 0; win < 32; ++win) {
    const int p = win & 1;
    const char* hb = lds + (p << 14);
    const char* vb = lds + 32768 + (p << 10);

    // stage next window into the other buffer (drained by this iter's barrier)
    if (win + 1 < 32) {
      const int jn = (win + 1) << 7;
      char* hbn = lds + ((p ^ 1) << 14);
#pragma unroll
      for (int nt = 0; nt < 4; ++nt)
        gl16(hTw + hoff[nt] + jn, hbn + ((w * 4 + nt) << 10) + (lane << 4));
      if (w == 0)
        gl16(vw + jn + quad * 32 + l16 * 2,
             lds + 32768 + ((p ^ 1) << 10) + (lane << 4));
    }

    // masks: uint32 covering this wave's 32 j of rows l16 and 16+l16
    unsigned int m0 = *(const unsigned int*)(lds + 34816 + (l16 << 9) +
                                             ((win ^ l16) << 4) + (w << 2));
    unsigned int m1 = *(const unsigned int*)(lds + 34816 + ((16 + l16) << 9) +
                                             ((win ^ (16 + l16)) << 4) + (w << 2));
    // hT B-fragments: contiguous lane-order ds_read_b128
    bf16x8 bfr[4];
#pragma unroll
    for (int nt = 0; nt < 4; ++nt)
      bfr[nt] = *(const bf16x8*)(hb + ((w * 4 + nt) << 10) + (lane << 4));
    // vv2: broadcast reads {v,v2,v,v2} per j-pair
    float4 q[4];
#pragma unroll
    for (int c = 0; c < 4; ++c)
      q[c] = *(const float4*)(vb + (w << 8) + (quad << 6) + (c << 4));

#pragma unroll
    for (int mt = 0; mt < 2; ++mt) {
      unsigned int m8 = ((mt ? m1 : m0) >> (quad * 8)) & 0xffu;
      bf16x8 af;
#pragma unroll
      for (int c = 0; c < 4; ++c) {
        float p0 = fmaxf(u[mt] * q[c].x, u2[mt] * q[c].y);
        float p1 = fmaxf(u[mt] * q[c].z, u2[mt] * q[c].w);
        af[2 * c]     = ((m8 >> (2 * c)) & 1u)     ? (__bf16)p0 : (__bf16)0.f;
        af[2 * c + 1] = ((m8 >> (2 * c + 1)) & 1u) ? (__bf16)p1 : (__bf16)0.f;
      }
#pragma unroll
      for (int nt = 0; nt < 4; ++nt)
        acc[mt][nt] = __builtin_amdgcn_mfma_f32_16x16x32_bf16(af, bfr[nt],
                                                              acc[mt][nt], 0, 0, 0);
      lacc[mt] = __builtin_amdgcn_mfma_f32_16x16x32_bf16(af, ones, lacc[mt], 0, 0, 0);
    }
    __syncthreads();
  }

  // epilogue: partials into LDS (aliases dead staging buffers), combine 4 waves
  float* accs = (float*)lds;             // [4][32][68]
  float* lsum = (float*)(lds + 34816);   // [4][32]
#pragma unroll
  for (int mt = 0; mt < 2; ++mt)
#pragma unroll
    for (int reg = 0; reg < 4; ++reg) {
      int row = mt * 16 + quad * 4 + reg;
      float* ap = accs + (w * 32 + row) * 68;
#pragma unroll
      for (int nt = 0; nt < 4; ++nt)
        ap[nt * 16 + l16] = acc[mt][nt][reg];
      if (l16 == 0) lsum[w * 32 + row] = lacc[mt][reg];
    }
  __syncthreads();

  const int r = t >> 3, c = (t & 7) * 8;
  float l = lsum[r] + lsum[32 + r] + lsum[64 + r] + lsum[96 + r];
  float inv = 1.0f / l;
  float o[8];
#pragma unroll
  for (int k = 0; k < 8; ++k)
    o[k] = (accs[r * 68 + c + k] + accs[(32 + r) * 68 + c + k] +
            accs[(64 + r) * 68 + c + k] + accs[(96 + r) * 68 + c + k]) * inv;
  float* op = out + (size_t)(i0 + r) * 256 + hh * 64 + c;
  *(float4*)op = make_float4(o[0], o[1], o[2], o[3]);
  *(float4*)(op + 4) = make_float4(o[4], o[5], o[6], o[7]);
}

extern "C" void kernel_launch(void* const* d_in, const int* in_sizes, int n_in,
                              void* d_out, int out_size, void* d_ws, size_t ws_size,
                              hipStream_t stream) {
  const float* x  = (const float*)d_in[0];
  const int*   adj = (const int*)d_in[1];
  const float* W  = (const float*)d_in[2];
  const float* a1 = (const float*)d_in[3];
  const float* a2 = (const float*)d_in[4];
  float* out = (float*)d_out;
  char* ws = (char*)d_ws;

  // ws layout (bytes):
  //   hT   bf16   [4][64][4096] @ 0        (2 MiB)
  //   siT  f32    [4][4096]     @ 2097152  (64 KiB)
  //   vv2T f32x2  [4][4096]     @ 2162688  (128 KiB)
  //   sjm  f32    [128][4]      @ 2293760  (2 KiB)
  //   adjb u8     [4096][512]   @ 2295808  (2 MiB bitmask)
  __bf16* hT   = (__bf16*)ws;
  float*  siT  = (float*)(ws + 2097152);
  float2* vv2T = (float2*)(ws + 2162688);
  float*  sjm  = (float*)(ws + 2293760);
  unsigned char* adjb = (unsigned char*)(ws + 2295808);

  gat_pack<<<2048, 256, 0, stream>>>(adj, adjb);
  gat_prep<<<dim3(128, 4), 256, 0, stream>>>(x, W, a1, a2, hT, siT, vv2T, sjm);
  gat_attn<<<dim3(128, 4), 256, 0, stream>>>(hT, siT, vv2T, sjm, adjb, out);
}